// Round 4
// baseline (226.125 us; speedup 1.0000x reference)
//
#include <hip/hip_runtime.h>
#include <hip/hip_bf16.h>

// Problem constants (fixed by reference setup)
#define B 32
#define HW 16384           // h*w = 128*128 per (b,c) row
#define NROW 128
#define POOL 8
#define GTW 1024           // W = 128*8
#define TOTAL (B * HW)     // 524288
#define NBLK (B * 2)       // select/loss blocks: row x {conv,tran}

// ws layout: [0..7] double acc | [8..11] uint counter | [64..] float dg[TOTAL]

// -------------------- K1: 8x8 block-sum pooling + zero accumulators -------
__global__ __launch_bounds__(256) void pool_kernel(const float* __restrict__ gt,
                                                   float* __restrict__ dg,
                                                   double* __restrict__ acc,
                                                   unsigned* __restrict__ cnt) {
    int out = blockIdx.x * 256 + threadIdx.x;     // 0 .. TOTAL-1
    if (out == 0) { *acc = 0.0; *cnt = 0u; }      // zero before K2 (stream-ordered)
    int b   = out >> 14;
    int rem = out & (HW - 1);
    int oi  = rem >> 7;
    int oj  = rem & (NROW - 1);
    const float* base = gt + ((size_t)b << 20) + (size_t)(oi * POOL) * GTW + oj * POOL;
    float s = 0.f;
#pragma unroll
    for (int r = 0; r < POOL; ++r) {
        const float4* p = reinterpret_cast<const float4*>(base + (size_t)r * GTW);
        float4 a = p[0];
        float4 c = p[1];
        s += a.x + a.y + a.z + a.w + c.x + c.y + c.z + c.w;
    }
    dg[out] = s;
}

// -------------------- K2: fused exact-top-k threshold + masked MSE --------
// blockIdx.x = row*2 + which  (which: 0 = conv-side mse, 1 = tran-side mse)
__global__ __launch_bounds__(256) void selloss_kernel(const float* __restrict__ dc_all,
                                                      const float* __restrict__ dt_all,
                                                      const float* __restrict__ dg_all,
                                                      const int* __restrict__ process,
                                                      double* __restrict__ acc,
                                                      unsigned* __restrict__ cnt,
                                                      float* __restrict__ out) {
    int b     = blockIdx.x >> 1;
    int which = blockIdx.x & 1;
    const float* dm = (which ? dt_all : dc_all) + (size_t)b * HW;  // "my" map
    const float* dq = (which ? dc_all : dt_all) + (size_t)b * HW;  // other map (for comb)
    const float* dg = dg_all + (size_t)b * HW;

    int p = process[0];
    int num = (int)(16384.0 * (0.1 * (double)p));   // matches Python int() truncation
    if (num > HW) num = HW;
    float w = (float)(1.0 * (double)p);

    int t = threadIdx.x;

    __shared__ unsigned s_lo, s_hi;
    __shared__ unsigned long long s_pk[4];
    __shared__ float s_mn[4], s_mx[4];
    __shared__ double s_d[4];

    float thr = __uint_as_float(0x7F800000u);       // +inf: select nothing (num<1 path)

    if (num >= 1) {
        // ---- phase 1: row errs in registers, exact k-th largest via
        //      min/max-narrowed quad-section over f32 bit patterns ----
        float e[64];
#pragma unroll
        for (int i = 0; i < 64; ++i) {
            int idx = i * 256 + t;                  // coalesced
            e[i] = fabsf(dg[idx] - dm[idx]);
        }

        float mn = e[0], mx = e[0];
#pragma unroll
        for (int i = 1; i < 64; ++i) { mn = fminf(mn, e[i]); mx = fmaxf(mx, e[i]); }
#pragma unroll
        for (int off = 32; off > 0; off >>= 1) {
            mn = fminf(mn, __shfl_down(mn, off, 64));
            mx = fmaxf(mx, __shfl_down(mx, off, 64));
        }
        if ((t & 63) == 0) { s_mn[t >> 6] = mn; s_mx[t >> 6] = mx; }
        __syncthreads();
        if (t == 0) {
            float a = fminf(fminf(s_mn[0], s_mn[1]), fminf(s_mn[2], s_mn[3]));
            float z = fmaxf(fmaxf(s_mx[0], s_mx[1]), fmaxf(s_mx[2], s_mx[3]));
            s_lo = __float_as_uint(a);              // cnt(>=min) = 16384 >= num
            s_hi = __float_as_uint(z) + 1u;         // cnt(>=max+ulp) = 0 < num
        }
        __syncthreads();

        // invariant: cnt(err >= f(s_lo)) >= num, cnt(err >= f(s_hi)) < num
        unsigned lo, hi;
        while (true) {
            lo = s_lo; hi = s_hi;
            unsigned r = hi - lo;
            if (r <= 1u) break;
            unsigned long long pk;
            unsigned q = 0;
            if (r >= 4u) {
                q = r >> 2;
                float m1 = __uint_as_float(lo + q);
                float m2 = __uint_as_float(lo + 2u * q);
                float m3 = __uint_as_float(lo + 3u * q);
                unsigned c1 = 0, c2 = 0, c3 = 0;
#pragma unroll
                for (int i = 0; i < 64; ++i) {
                    c1 += (e[i] >= m1);
                    c2 += (e[i] >= m2);
                    c3 += (e[i] >= m3);
                }
                pk = (unsigned long long)c1 | ((unsigned long long)c2 << 21) |
                     ((unsigned long long)c3 << 42);
            } else {
                unsigned m = lo + (r >> 1);
                float fm = __uint_as_float(m);
                unsigned c = 0;
#pragma unroll
                for (int i = 0; i < 64; ++i) c += (e[i] >= fm);
                pk = (unsigned long long)c;
            }
#pragma unroll
            for (int off = 32; off > 0; off >>= 1) pk += __shfl_down(pk, off, 64);
            if ((t & 63) == 0) s_pk[t >> 6] = pk;
            __syncthreads();
            if (t == 0) {
                unsigned long long tot = s_pk[0] + s_pk[1] + s_pk[2] + s_pk[3];
                if (r >= 4u) {
                    int C1 = (int)(tot & 0x1FFFFFu);
                    int C2 = (int)((tot >> 21) & 0x1FFFFFu);
                    int C3 = (int)((tot >> 42) & 0x1FFFFFu);
                    if      (C1 < num)  s_hi = lo + q;
                    else if (C2 < num) { s_lo = lo + q;      s_hi = lo + 2u * q; }
                    else if (C3 < num) { s_lo = lo + 2u * q; s_hi = lo + 3u * q; }
                    else                s_lo = lo + 3u * q;
                } else {
                    unsigned m = lo + (r >> 1);
                    if ((int)tot < num) s_hi = m; else s_lo = m;
                }
            }
            __syncthreads();
        }
        thr = __uint_as_float(lo);                  // exact num-th largest value
    }

    // ---- phase 2: this (row, side)'s masked-MSE contribution (L2/L3-hot) ----
    double lacc = 0.0;
#pragma unroll 8
    for (int i = 0; i < 64; ++i) {
        int idx = i * 256 + t;
        float m_ = dm[idx];
        float o_ = dq[idx];
        float g  = dg[idx];
        float err   = fabsf(g - m_);
        float combo = w * o_ + (1.0f - w) * g;      // comb of the OTHER map
        float sup   = (err >= thr) ? combo : g;     // inf thr -> dg (num<1 path)
        float d     = m_ - sup;
        lacc += (double)(d * d);
    }

#pragma unroll
    for (int off = 32; off > 0; off >>= 1) lacc += __shfl_down(lacc, off, 64);
    if ((t & 63) == 0) s_d[t >> 6] = lacc;
    __syncthreads();
    if (t == 0) {
        double tot = s_d[0] + s_d[1] + s_d[2] + s_d[3];
        atomicAdd(acc, tot);
        __threadfence();
        unsigned old = atomicAdd(cnt, 1u);
        if (old == NBLK - 1) {                      // last block publishes the scalar
            double fin = atomicAdd(acc, 0.0);       // coherent read of final sum
            out[0] = (float)fin;
        }
    }
}

extern "C" void kernel_launch(void* const* d_in, const int* in_sizes, int n_in,
                              void* d_out, int out_size, void* d_ws, size_t ws_size,
                              hipStream_t stream) {
    const float* dmap_conv = (const float*)d_in[0];
    const float* dmap_tran = (const float*)d_in[1];
    const float* gt        = (const float*)d_in[2];
    const int*   process   = (const int*)d_in[3];
    float* out = (float*)d_out;

    char* ws = (char*)d_ws;
    double*   acc = (double*)ws;
    unsigned* cnt = (unsigned*)(ws + 8);
    float*    dg  = (float*)(ws + 64);              // 2 MB

    pool_kernel<<<TOTAL / 256, 256, 0, stream>>>(gt, dg, acc, cnt);
    selloss_kernel<<<NBLK, 256, 0, stream>>>(dmap_conv, dmap_tran, dg, process, acc, cnt, out);
}

// Round 8
// 218.610 us; speedup vs baseline: 1.0344x; 1.0344x over previous
//
#include <hip/hip_runtime.h>
#include <hip/hip_bf16.h>

// Problem constants (fixed by reference setup)
#define B 32
#define HW 16384           // h*w = 128*128 per (b,c) row
#define NROW 128
#define POOL 8
#define GTW 1024           // W = 128*8
#define TOTAL (B * HW)     // 524288
#define NBLK (B * 2)       // selloss blocks: row x {conv,tran}
#define ST 512             // selloss threads/block (8 waves)

// ws layout: [0..7] double acc | [8..11] uint counter | [64..] float dg[TOTAL]

// -------------------- K1: 8x8 block-sum pooling + zero accumulators -------
__global__ __launch_bounds__(256) void pool_kernel(const float* __restrict__ gt,
                                                   float* __restrict__ dg,
                                                   double* __restrict__ acc,
                                                   unsigned* __restrict__ cnt) {
    int out = blockIdx.x * 256 + threadIdx.x;     // 0 .. TOTAL-1
    if (out == 0) { *acc = 0.0; *cnt = 0u; }      // zero before K2 (stream-ordered)
    int b   = out >> 14;
    int rem = out & (HW - 1);
    int oi  = rem >> 7;
    int oj  = rem & (NROW - 1);
    const float* base = gt + ((size_t)b << 20) + (size_t)(oi * POOL) * GTW + oj * POOL;
    float s = 0.f;
#pragma unroll
    for (int r = 0; r < POOL; ++r) {
        const float4* p = reinterpret_cast<const float4*>(base + (size_t)r * GTW);
        float4 a = p[0];
        float4 c = p[1];
        s += a.x + a.y + a.z + a.w + c.x + c.y + c.z + c.w;
    }
    dg[out] = s;
}

// -------------------- K2: fused exact-top-k threshold + masked MSE --------
// blockIdx.x = row*2 + which  (which: 0 = conv-side mse, 1 = tran-side mse)
// 512 threads = 8 waves; each thread owns 32 row elements (8 x float4).
__global__ __launch_bounds__(ST) void selloss_kernel(const float* __restrict__ dc_all,
                                                     const float* __restrict__ dt_all,
                                                     const float* __restrict__ dg_all,
                                                     const int* __restrict__ process,
                                                     double* __restrict__ acc,
                                                     unsigned* __restrict__ cnt,
                                                     float* __restrict__ out) {
    int b     = blockIdx.x >> 1;
    int which = blockIdx.x & 1;
    const float* dm = (which ? dt_all : dc_all) + (size_t)b * HW;  // "my" map
    const float* dq = (which ? dc_all : dt_all) + (size_t)b * HW;  // other map (for comb)
    const float* dg = dg_all + (size_t)b * HW;

    int p = process[0];
    int num = (int)(16384.0 * (0.1 * (double)p));   // matches Python int() truncation
    if (num > HW) num = HW;
    float w = (float)(1.0 * (double)p);

    int t = threadIdx.x;

    __shared__ unsigned s_lo, s_hi;
    __shared__ unsigned long long s_pk[8];
    __shared__ float s_mn[8], s_mx[8];
    __shared__ double s_d[8];

    float thr = __uint_as_float(0x7F800000u);       // +inf: select nothing (num<1 path)

    if (num >= 1) {
        // ---- phase 1: row errs in registers (float4 loads), exact k-th
        //      largest via min/max-narrowed quad-section over f32 bits ----
        float e[32];
#pragma unroll
        for (int j = 0; j < 8; ++j) {
            int e4 = j * 2048 + t * 4;              // coalesced 16B/lane
            float4 g4 = *reinterpret_cast<const float4*>(dg + e4);
            float4 m4 = *reinterpret_cast<const float4*>(dm + e4);
            e[j * 4 + 0] = fabsf(g4.x - m4.x);
            e[j * 4 + 1] = fabsf(g4.y - m4.y);
            e[j * 4 + 2] = fabsf(g4.z - m4.z);
            e[j * 4 + 3] = fabsf(g4.w - m4.w);
        }

        float mn = e[0], mx = e[0];
#pragma unroll
        for (int i = 1; i < 32; ++i) { mn = fminf(mn, e[i]); mx = fmaxf(mx, e[i]); }
#pragma unroll
        for (int off = 32; off > 0; off >>= 1) {
            mn = fminf(mn, __shfl_down(mn, off, 64));
            mx = fmaxf(mx, __shfl_down(mx, off, 64));
        }
        if ((t & 63) == 0) { s_mn[t >> 6] = mn; s_mx[t >> 6] = mx; }
        __syncthreads();
        if (t == 0) {
            float a = s_mn[0], z = s_mx[0];
#pragma unroll
            for (int i = 1; i < 8; ++i) { a = fminf(a, s_mn[i]); z = fmaxf(z, s_mx[i]); }
            s_lo = __float_as_uint(a);              // cnt(>=min) = 16384 >= num
            s_hi = __float_as_uint(z) + 1u;         // cnt(>=max+ulp) = 0 < num
        }
        __syncthreads();

        // invariant: cnt(err >= f(s_lo)) >= num, cnt(err >= f(s_hi)) < num
        unsigned lo, hi;
        while (true) {
            lo = s_lo; hi = s_hi;
            unsigned r = hi - lo;
            if (r <= 1u) break;
            unsigned long long pk;
            unsigned q = 0;
            if (r >= 4u) {
                q = r >> 2;
                float m1 = __uint_as_float(lo + q);
                float m2 = __uint_as_float(lo + 2u * q);
                float m3 = __uint_as_float(lo + 3u * q);
                unsigned c1 = 0, c2 = 0, c3 = 0;
#pragma unroll
                for (int i = 0; i < 32; ++i) {
                    c1 += (e[i] >= m1);
                    c2 += (e[i] >= m2);
                    c3 += (e[i] >= m3);
                }
                pk = (unsigned long long)c1 | ((unsigned long long)c2 << 21) |
                     ((unsigned long long)c3 << 42);
            } else {
                unsigned m = lo + (r >> 1);
                float fm = __uint_as_float(m);
                unsigned c = 0;
#pragma unroll
                for (int i = 0; i < 32; ++i) c += (e[i] >= fm);
                pk = (unsigned long long)c;
            }
#pragma unroll
            for (int off = 32; off > 0; off >>= 1) pk += __shfl_down(pk, off, 64);
            if ((t & 63) == 0) s_pk[t >> 6] = pk;
            __syncthreads();
            if (t == 0) {
                unsigned long long tot = 0ull;
#pragma unroll
                for (int i = 0; i < 8; ++i) tot += s_pk[i];
                if (r >= 4u) {
                    int C1 = (int)(tot & 0x1FFFFFu);
                    int C2 = (int)((tot >> 21) & 0x1FFFFFu);
                    int C3 = (int)((tot >> 42) & 0x1FFFFFu);
                    if      (C1 < num)  s_hi = lo + q;
                    else if (C2 < num) { s_lo = lo + q;      s_hi = lo + 2u * q; }
                    else if (C3 < num) { s_lo = lo + 2u * q; s_hi = lo + 3u * q; }
                    else                s_lo = lo + 3u * q;
                } else {
                    unsigned m = lo + (r >> 1);
                    if ((int)tot < num) s_hi = m; else s_lo = m;
                }
            }
            __syncthreads();
        }
        thr = __uint_as_float(lo);                  // exact num-th largest value
    }

    // ---- phase 2: this (row, side)'s masked-MSE contribution (L2/L3-hot) ----
    double lacc = 0.0;
#pragma unroll
    for (int j = 0; j < 8; ++j) {
        int e4 = j * 2048 + t * 4;
        float4 m4 = *reinterpret_cast<const float4*>(dm + e4);
        float4 o4 = *reinterpret_cast<const float4*>(dq + e4);
        float4 g4 = *reinterpret_cast<const float4*>(dg + e4);
        const float mv[4] = {m4.x, m4.y, m4.z, m4.w};
        const float ov[4] = {o4.x, o4.y, o4.z, o4.w};
        const float gv[4] = {g4.x, g4.y, g4.z, g4.w};
#pragma unroll
        for (int k = 0; k < 4; ++k) {
            float err   = fabsf(gv[k] - mv[k]);
            float combo = w * ov[k] + (1.0f - w) * gv[k];   // comb of the OTHER map
            float sup   = (err >= thr) ? combo : gv[k];     // inf thr -> dg (num<1)
            float d     = mv[k] - sup;
            lacc += (double)(d * d);
        }
    }

#pragma unroll
    for (int off = 32; off > 0; off >>= 1) lacc += __shfl_down(lacc, off, 64);
    if ((t & 63) == 0) s_d[t >> 6] = lacc;
    __syncthreads();
    if (t == 0) {
        double tot = 0.0;
#pragma unroll
        for (int i = 0; i < 8; ++i) tot += s_d[i];
        atomicAdd(acc, tot);
        __threadfence();
        unsigned old = atomicAdd(cnt, 1u);
        if (old == NBLK - 1) {                      // last block publishes the scalar
            double fin = atomicAdd(acc, 0.0);       // coherent read of final sum
            out[0] = (float)fin;
        }
    }
}

extern "C" void kernel_launch(void* const* d_in, const int* in_sizes, int n_in,
                              void* d_out, int out_size, void* d_ws, size_t ws_size,
                              hipStream_t stream) {
    const float* dmap_conv = (const float*)d_in[0];
    const float* dmap_tran = (const float*)d_in[1];
    const float* gt        = (const float*)d_in[2];
    const int*   process   = (const int*)d_in[3];
    float* out = (float*)d_out;

    char* ws = (char*)d_ws;
    double*   acc = (double*)ws;
    unsigned* cnt = (unsigned*)(ws + 8);
    float*    dg  = (float*)(ws + 64);              // 2 MB

    pool_kernel<<<TOTAL / 256, 256, 0, stream>>>(gt, dg, acc, cnt);
    selloss_kernel<<<NBLK, ST, 0, stream>>>(dmap_conv, dmap_tran, dg, process, acc, cnt, out);
}